// Round 2
// baseline (115.831 us; speedup 1.0000x reference)
//
#include <hip/hip_runtime.h>

#define T_TOK 32768
#define E_EXP 256
#define K_SEL 8
#define D_DEV 8
#define SLOTS (E_EXP / D_DEV)        // 32 experts per device
#define NBLK  1024
#define TOK_PER_BLK (T_TOK / NBLK)   // 32 tokens per block
#define PAIRS_PER_WAVE (TOK_PER_BLK / 2 / 4)  // 4 pair-iterations per wave

// Single fused kernel:
//  - per-block expert setup (dev_of_expert + stable-sort rank) via ballots
//  - per-wave token-pair processing: gather K=8 selected scores, scatter into
//    the device-remapped [D][T][SLOTS] layout, zeros elsewhere
//  - reduced_mask row (OR over the token pair) computed wave-locally
__global__ __launch_bounds__(256) void moe_fused_kernel(
    const float* __restrict__ topk, const int* __restrict__ mapping,
    const int* __restrict__ meta, float* __restrict__ out_remap,
    float* __restrict__ out_mask) {
  __shared__ int sdev[E_EXP];
  __shared__ int spos[E_EXP];
  __shared__ int scnt[4 * D_DEV];   // per-wave per-device counts

  const int tid  = threadIdx.x;
  const int w    = tid >> 6;
  const int lane = tid & 63;

  // ---------------- per-block expert setup: thread tid = expert tid --------
  {
    const int e = tid;
    int4 m0 = ((const int4*)mapping)[e * 2];
    int4 m1 = ((const int4*)mapping)[e * 2 + 1];
    int vals[8] = {m0.x, m0.y, m0.z, m0.w, m1.x, m1.y, m1.z, m1.w};
    int best = vals[0], dev = 0;
#pragma unroll
    for (int d = 1; d < 8; ++d)
      if (vals[d] > best) { best = vals[d]; dev = d; }
    sdev[e] = dev;

    // stable rank: ballot per device (all lanes see result)
    unsigned long long myball = 0ull;
#pragma unroll
    for (int d = 0; d < 8; ++d) {
      unsigned long long b = __ballot(dev == d);
      if (d == dev) myball = b;                 // cndmask, no scratch array
      if (lane == d) scnt[w * 8 + d] = __popcll(b);
    }
    const unsigned long long lt =
        (lane == 0) ? 0ull : (~0ull >> (64 - lane));
    const int lower = __popcll(myball & lt);
    __syncthreads();
    int base = 0;
    for (int d = 0; d < dev; ++d)
      base += scnt[0 * 8 + d] + scnt[1 * 8 + d] + scnt[2 * 8 + d] +
              scnt[3 * 8 + d];
    for (int w2 = 0; w2 < w; ++w2) base += scnt[w2 * 8 + dev];
    spos[e] = base + lower;
    __syncthreads();
  }

  // this lane's 4 experts -> output positions (fixed across tokens)
  const int e0 = lane * 4;
  const int p0 = spos[e0], p1 = spos[e0 + 1], p2 = spos[e0 + 2],
            p3 = spos[e0 + 3];
  const bool contig =
      (p1 == p0 + 1) && (p2 == p0 + 2) && (p3 == p0 + 3) && ((p0 & 3) == 0);
  float* const contig_base =
      out_remap + (size_t)(p0 >> 5) * T_TOK * SLOTS + (p0 & 31);

  const int tok_base = blockIdx.x * TOK_PER_BLK;

#pragma unroll
  for (int j = 0; j < PAIRS_PER_WAVE; ++j) {
    const int pair = w + 4 * j;        // pair index within block
    const int t0 = tok_base + 2 * pair;
    unsigned dmask = 0;

#pragma unroll
    for (int s = 0; s < 2; ++s) {
      const int t = t0 + s;
      const int4* mp = (const int4*)(meta + (size_t)t * K_SEL);
      int4 a = mp[0], b = mp[1];
      int mv[8] = {a.x, a.y, a.z, a.w, b.x, b.y, b.z, b.w};

      float4 v = {0.f, 0.f, 0.f, 0.f};
      const float* row = topk + (size_t)t * E_EXP;
#pragma unroll
      for (int k = 0; k < K_SEL; ++k) {
        const int e = mv[k];
        dmask |= 1u << sdev[e];        // LDS broadcast (uniform addr)
        if ((e >> 2) == lane) {        // 1 lane active: gather selected score
          const float x = row[e];
          const int slot = e & 3;
          if (slot == 0) v.x = x;
          else if (slot == 1) v.y = x;
          else if (slot == 2) v.z = x;
          else v.w = x;
        }
      }

      if (contig) {
        *(float4*)(contig_base + (size_t)t * SLOTS) = v;
      } else {
        float vv[4] = {v.x, v.y, v.z, v.w};
        int pp[4] = {p0, p1, p2, p3};
#pragma unroll
        for (int i = 0; i < 4; ++i)
          out_remap[(size_t)(pp[i] >> 5) * T_TOK * SLOTS + (size_t)t * SLOTS +
                    (pp[i] & 31)] = vv[i];
      }
    }

    // reduced_mask row for this pair (dmask identical across lanes)
    if (lane < 8) {
      const int rowi = t0 >> 1;
      out_mask[(size_t)rowi * D_DEV + lane] =
          ((dmask >> lane) & 1u) ? 1.0f : 0.0f;
    }
  }
}

extern "C" void kernel_launch(void* const* d_in, const int* in_sizes, int n_in,
                              void* d_out, int out_size, void* d_ws, size_t ws_size,
                              hipStream_t stream) {
  const float* topk    = (const float*)d_in[0];
  const int*   mapping = (const int*)d_in[1];
  const int*   meta    = (const int*)d_in[2];

  float* out_remap = (float*)d_out;
  float* out_mask  = out_remap + (size_t)D_DEV * T_TOK * SLOTS;  // 8,388,608

  moe_fused_kernel<<<NBLK, 256, 0, stream>>>(topk, mapping, meta, out_remap,
                                             out_mask);
}

// Round 3
// 90.272 us; speedup vs baseline: 1.2831x; 1.2831x over previous
//
#include <hip/hip_runtime.h>

#define T_TOK 32768
#define E_EXP 256
#define K_SEL 8
#define D_DEV 8
#define SLOTS (E_EXP / D_DEV)      // 32 experts per device
#define NBLK  1024
#define TOK_PER_BLK (T_TOK / NBLK) // 32 tokens per block
#define TOK_PER_WAVE (TOK_PER_BLK / 4)  // 8 tokens per wave

// Fused kernel:
//  - per-block expert setup (dev_of_expert + stable rank) via wave ballots
//  - streaming main loop: wave per token, lane owns 4 consecutive experts,
//    float4 read of topk row, gate by 8 meta compares, float4 write to the
//    device-remapped [D][T][SLOTS] layout. 4 tokens in flight per iteration.
//  - reduced_mask per token-pair via 8 wave ballots (no LDS in hot loop)
__global__ __launch_bounds__(256) void moe_fused_kernel(
    const float* __restrict__ topk, const int* __restrict__ mapping,
    const int* __restrict__ meta, float* __restrict__ out_remap,
    float* __restrict__ out_mask) {
  __shared__ int sdev[E_EXP];
  __shared__ int spos[E_EXP];
  __shared__ int scnt[4 * D_DEV];

  const int tid  = threadIdx.x;
  const int w    = tid >> 6;
  const int lane = tid & 63;

  // ---------------- per-block expert setup: thread tid = expert tid --------
  {
    const int e = tid;
    int4 m0 = ((const int4*)mapping)[e * 2];
    int4 m1 = ((const int4*)mapping)[e * 2 + 1];
    int vals[8] = {m0.x, m0.y, m0.z, m0.w, m1.x, m1.y, m1.z, m1.w};
    int best = vals[0], dev = 0;
#pragma unroll
    for (int d = 1; d < 8; ++d)
      if (vals[d] > best) { best = vals[d]; dev = d; }
    sdev[e] = dev;

    unsigned long long myball = 0ull;
#pragma unroll
    for (int d = 0; d < 8; ++d) {
      unsigned long long b = __ballot(dev == d);
      if (d == dev) myball = b;
      if (lane == d) scnt[w * 8 + d] = __popcll(b);
    }
    const unsigned long long lt = (lane == 0) ? 0ull : (~0ull >> (64 - lane));
    const int lower = __popcll(myball & lt);
    __syncthreads();
    int base = 0;
    for (int d = 0; d < dev; ++d)
      base += scnt[0 * 8 + d] + scnt[1 * 8 + d] + scnt[2 * 8 + d] +
              scnt[3 * 8 + d];
    for (int w2 = 0; w2 < w; ++w2) base += scnt[w2 * 8 + dev];
    spos[e] = base + lower;
    __syncthreads();
  }

  // per-lane constants: positions + devices of experts [lane*4, lane*4+4)
  const int e0 = lane * 4;
  const int p0 = spos[e0], p1 = spos[e0 + 1], p2 = spos[e0 + 2],
            p3 = spos[e0 + 3];
  const int dv0 = sdev[e0], dv1 = sdev[e0 + 1], dv2 = sdev[e0 + 2],
            dv3 = sdev[e0 + 3];
  const bool contig =
      (p1 == p0 + 1) && (p2 == p0 + 2) && (p3 == p0 + 3) && ((p0 & 3) == 0);
  float* const contig_base =
      out_remap + (size_t)(p0 >> 5) * T_TOK * SLOTS + (p0 & 31);

  const int tok0 = __builtin_amdgcn_readfirstlane(
      blockIdx.x * TOK_PER_BLK + w * TOK_PER_WAVE);

#pragma unroll
  for (int j = 0; j < TOK_PER_WAVE; j += 4) {   // 4 tokens (2 pairs) / iter
    const int tbase = tok0 + j;

    float4 v[4];
    int mv[4][8];
#pragma unroll
    for (int s = 0; s < 4; ++s) {
      const int t = tbase + s;
      v[s] = *(const float4*)(topk + (size_t)t * E_EXP + e0);
      const int4* mp = (const int4*)(meta + (size_t)t * K_SEL);
      int4 a = mp[0], b = mp[1];
      mv[s][0] = a.x; mv[s][1] = a.y; mv[s][2] = a.z; mv[s][3] = a.w;
      mv[s][4] = b.x; mv[s][5] = b.y; mv[s][6] = b.z; mv[s][7] = b.w;
    }

    unsigned ldm[4];
#pragma unroll
    for (int s = 0; s < 4; ++s) {
      unsigned sel = 0;
#pragma unroll
      for (int k = 0; k < K_SEL; ++k)
        sel |= ((mv[s][k] >> 2) == lane) ? (1u << (mv[s][k] & 3)) : 0u;
      v[s].x = (sel & 1u) ? v[s].x : 0.0f;
      v[s].y = (sel & 2u) ? v[s].y : 0.0f;
      v[s].z = (sel & 4u) ? v[s].z : 0.0f;
      v[s].w = (sel & 8u) ? v[s].w : 0.0f;
      ldm[s] = ((sel & 1u) ? (1u << dv0) : 0u) |
               ((sel & 2u) ? (1u << dv1) : 0u) |
               ((sel & 4u) ? (1u << dv2) : 0u) |
               ((sel & 8u) ? (1u << dv3) : 0u);
    }

#pragma unroll
    for (int s = 0; s < 4; ++s) {
      const int t = tbase + s;
      if (contig) {
        *(float4*)(contig_base + (size_t)t * SLOTS) = v[s];
      } else {
        float vv[4] = {v[s].x, v[s].y, v[s].z, v[s].w};
        int pp[4] = {p0, p1, p2, p3};
#pragma unroll
        for (int i = 0; i < 4; ++i)
          out_remap[(size_t)(pp[i] >> 5) * T_TOK * SLOTS + (size_t)t * SLOTS +
                    (pp[i] & 31)] = vv[i];
      }
    }

    // reduced_mask: one row per pair, OR across lanes via ballots
#pragma unroll
    for (int pr = 0; pr < 2; ++pr) {
      const unsigned comb = ldm[2 * pr] | ldm[2 * pr + 1];
      float fm = 0.0f;
#pragma unroll
      for (int d = 0; d < D_DEV; ++d) {
        const unsigned long long b = __ballot((comb >> d) & 1u);
        if (lane == d) fm = (b != 0ull) ? 1.0f : 0.0f;
      }
      if (lane < 8) {
        const int rowi = (tbase + 2 * pr) >> 1;
        out_mask[(size_t)rowi * D_DEV + lane] = fm;
      }
    }
  }
}

extern "C" void kernel_launch(void* const* d_in, const int* in_sizes, int n_in,
                              void* d_out, int out_size, void* d_ws, size_t ws_size,
                              hipStream_t stream) {
  const float* topk    = (const float*)d_in[0];
  const int*   mapping = (const int*)d_in[1];
  const int*   meta    = (const int*)d_in[2];

  float* out_remap = (float*)d_out;
  float* out_mask  = out_remap + (size_t)D_DEV * T_TOK * SLOTS;  // 8,388,608

  moe_fused_kernel<<<NBLK, 256, 0, stream>>>(topk, mapping, meta, out_remap,
                                             out_mask);
}

// Round 4
// 87.602 us; speedup vs baseline: 1.3222x; 1.0305x over previous
//
#include <hip/hip_runtime.h>

#define T_TOK 32768
#define E_EXP 256
#define K_SEL 8
#define D_DEV 8
#define SLOTS (E_EXP / D_DEV)      // 32 experts per device
#define NBLK  2048
#define TOK_PER_BLK (T_TOK / NBLK) // 16 tokens per block
#define TOK_PER_WAVE (TOK_PER_BLK / 4)  // 4 tokens per wave (one iteration)

// Fused kernel:
//  - per-block expert setup (dev_of_expert + stable rank) via wave ballots
//  - streaming: wave handles 4 tokens (2 mask pairs); lane owns 4 consecutive
//    experts; float4 read of topk row, gate by 8 meta compares, float4 write
//    to the device-remapped [D][T][SLOTS] layout. All 4 loads in flight.
//  - reduced_mask per pair via 6-step shfl_xor OR butterfly
// grid 2048 x 256: 8 blocks/CU co-resident -> 32 waves/CU (100% occ ceiling)
__global__ __launch_bounds__(256) void moe_fused_kernel(
    const float* __restrict__ topk, const int* __restrict__ mapping,
    const int* __restrict__ meta, float* __restrict__ out_remap,
    float* __restrict__ out_mask) {
  __shared__ int sdev[E_EXP];
  __shared__ int spos[E_EXP];
  __shared__ int scnt[4 * D_DEV];

  const int tid  = threadIdx.x;
  const int w    = tid >> 6;
  const int lane = tid & 63;

  // ---------------- per-block expert setup: thread tid = expert tid --------
  {
    const int e = tid;
    int4 m0 = ((const int4*)mapping)[e * 2];
    int4 m1 = ((const int4*)mapping)[e * 2 + 1];
    int vals[8] = {m0.x, m0.y, m0.z, m0.w, m1.x, m1.y, m1.z, m1.w};
    int best = vals[0], dev = 0;
#pragma unroll
    for (int d = 1; d < 8; ++d)
      if (vals[d] > best) { best = vals[d]; dev = d; }
    sdev[e] = dev;

    unsigned long long myball = 0ull;
#pragma unroll
    for (int d = 0; d < 8; ++d) {
      unsigned long long b = __ballot(dev == d);
      if (d == dev) myball = b;
      if (lane == d) scnt[w * 8 + d] = __popcll(b);
    }
    const unsigned long long lt = (lane == 0) ? 0ull : (~0ull >> (64 - lane));
    const int lower = __popcll(myball & lt);
    __syncthreads();
    int base = 0;
    for (int d = 0; d < dev; ++d)
      base += scnt[0 * 8 + d] + scnt[1 * 8 + d] + scnt[2 * 8 + d] +
              scnt[3 * 8 + d];
    for (int w2 = 0; w2 < w; ++w2) base += scnt[w2 * 8 + dev];
    spos[e] = base + lower;
    __syncthreads();
  }

  // per-lane constants: positions + devices of experts [lane*4, lane*4+4)
  const int e0 = lane * 4;
  const int p0 = spos[e0], p1 = spos[e0 + 1], p2 = spos[e0 + 2],
            p3 = spos[e0 + 3];
  const int dv0 = sdev[e0], dv1 = sdev[e0 + 1], dv2 = sdev[e0 + 2],
            dv3 = sdev[e0 + 3];
  const bool contig =
      (p1 == p0 + 1) && (p2 == p0 + 2) && (p3 == p0 + 3) && ((p0 & 3) == 0);
  float* const contig_base =
      out_remap + (size_t)(p0 >> 5) * T_TOK * SLOTS + (p0 & 31);

  const int tbase = __builtin_amdgcn_readfirstlane(
      blockIdx.x * TOK_PER_BLK + w * TOK_PER_WAVE);

  // ---- all loads for 4 tokens issued up front (ILP) ----
  float4 v[4];
  int mv[4][8];
#pragma unroll
  for (int s = 0; s < 4; ++s) {
    const int t = tbase + s;
    v[s] = *(const float4*)(topk + (size_t)t * E_EXP + e0);
    const int4* mp = (const int4*)(meta + (size_t)t * K_SEL);
    int4 a = mp[0], b = mp[1];
    mv[s][0] = a.x; mv[s][1] = a.y; mv[s][2] = a.z; mv[s][3] = a.w;
    mv[s][4] = b.x; mv[s][5] = b.y; mv[s][6] = b.z; mv[s][7] = b.w;
  }

  unsigned ldm[4];
#pragma unroll
  for (int s = 0; s < 4; ++s) {
    unsigned sel = 0;
#pragma unroll
    for (int k = 0; k < K_SEL; ++k)
      sel |= ((mv[s][k] >> 2) == lane) ? (1u << (mv[s][k] & 3)) : 0u;
    v[s].x = (sel & 1u) ? v[s].x : 0.0f;
    v[s].y = (sel & 2u) ? v[s].y : 0.0f;
    v[s].z = (sel & 4u) ? v[s].z : 0.0f;
    v[s].w = (sel & 8u) ? v[s].w : 0.0f;
    ldm[s] = ((sel & 1u) ? (1u << dv0) : 0u) |
             ((sel & 2u) ? (1u << dv1) : 0u) |
             ((sel & 4u) ? (1u << dv2) : 0u) |
             ((sel & 8u) ? (1u << dv3) : 0u);
  }

#pragma unroll
  for (int s = 0; s < 4; ++s) {
    const int t = tbase + s;
    if (contig) {
      *(float4*)(contig_base + (size_t)t * SLOTS) = v[s];
    } else {
      float vv[4] = {v[s].x, v[s].y, v[s].z, v[s].w};
      int pp[4] = {p0, p1, p2, p3};
#pragma unroll
      for (int i = 0; i < 4; ++i)
        out_remap[(size_t)(pp[i] >> 5) * T_TOK * SLOTS + (size_t)t * SLOTS +
                  (pp[i] & 31)] = vv[i];
    }
  }

  // reduced_mask: one row per pair, OR across lanes via shfl_xor butterfly
#pragma unroll
  for (int pr = 0; pr < 2; ++pr) {
    unsigned comb = ldm[2 * pr] | ldm[2 * pr + 1];
#pragma unroll
    for (int off = 32; off >= 1; off >>= 1)
      comb |= (unsigned)__shfl_xor((int)comb, off, 64);
    if (lane < 8) {
      const int rowi = (tbase + 2 * pr) >> 1;
      out_mask[(size_t)rowi * D_DEV + lane] =
          ((comb >> lane) & 1u) ? 1.0f : 0.0f;
    }
  }
}

extern "C" void kernel_launch(void* const* d_in, const int* in_sizes, int n_in,
                              void* d_out, int out_size, void* d_ws, size_t ws_size,
                              hipStream_t stream) {
  const float* topk    = (const float*)d_in[0];
  const int*   mapping = (const int*)d_in[1];
  const int*   meta    = (const int*)d_in[2];

  float* out_remap = (float*)d_out;
  float* out_mask  = out_remap + (size_t)D_DEV * T_TOK * SLOTS;  // 8,388,608

  moe_fused_kernel<<<NBLK, 256, 0, stream>>>(topk, mapping, meta, out_remap,
                                             out_mask);
}

// Round 5
// 85.909 us; speedup vs baseline: 1.3483x; 1.0197x over previous
//
#include <hip/hip_runtime.h>

#define T_TOK 32768
#define E_EXP 256
#define K_SEL 8
#define D_DEV 8
#define SLOTS (E_EXP / D_DEV)        // 32 experts per device
#define NBLK  1024
#define TOK_PER_BLK (T_TOK / NBLK)   // 32 tokens per block
#define TOK_PER_WAVE (TOK_PER_BLK / 4)  // 8 tokens per wave

// Gather-based fused kernel.
//  Phase A (per block): expert setup (dev_of_expert + stable rank) via wave
//          ballots — overlapped with the meta/mapping load latency.
//  Phase B (per wave, 8 tokens): lane = one (token, k) pair. Gather the
//          selected score topk[t][e], scatter it by remapped position into a
//          per-wave dense LDS tile [8][256] pre-filled with zeros (gating by
//          construction — no compares). Device mask via 8 ballots on sdev[e].
//  Phase C: lane reads float4 tile[tt][lane*4] -> coalesced 1KB/token store
//          into out_remap[D][T][SLOTS]; lanes 0-31 write 4 mask rows (128 B).
// Reads only ~420 B/token of topk instead of the full 1 KB row.
__global__ __launch_bounds__(256) void moe_fused_kernel(
    const float* __restrict__ topk, const int* __restrict__ mapping,
    const int* __restrict__ meta, float* __restrict__ out_remap,
    float* __restrict__ out_mask) {
  __shared__ float tile[4][TOK_PER_WAVE * E_EXP];  // 32 KB, wave-private rows
  __shared__ int sdev[E_EXP];
  __shared__ int spos[E_EXP];
  __shared__ int scnt[4 * D_DEV];

  const int tid  = threadIdx.x;
  const int w    = tid >> 6;
  const int lane = tid & 63;
  const int tbase = blockIdx.x * TOK_PER_BLK + w * TOK_PER_WAVE;
  const int tok   = tbase + (lane >> 3);   // this lane's gather token
  // 1) meta load first: 64 consecutive dwords per wave (coalesced 256 B)
  const int e = meta[(size_t)tbase * K_SEL + lane];

  // 2) mapping loads (2 x int4 per thread), then zero the tile while in flight
  const int4 m0 = ((const int4*)mapping)[tid * 2];
  const int4 m1 = ((const int4*)mapping)[tid * 2 + 1];
  const float4 z4 = {0.f, 0.f, 0.f, 0.f};
#pragma unroll
  for (int i = 0; i < TOK_PER_WAVE; ++i)
    *(float4*)&tile[w][i * E_EXP + lane * 4] = z4;

  // 3) expert setup: thread tid = expert tid
  {
    int vals[8] = {m0.x, m0.y, m0.z, m0.w, m1.x, m1.y, m1.z, m1.w};
    int best = vals[0], dev = 0;
#pragma unroll
    for (int d = 1; d < 8; ++d)
      if (vals[d] > best) { best = vals[d]; dev = d; }
    sdev[tid] = dev;

    unsigned long long myball = 0ull;
#pragma unroll
    for (int d = 0; d < 8; ++d) {
      unsigned long long b = __ballot(dev == d);
      if (d == dev) myball = b;
      if (lane == d) scnt[w * 8 + d] = __popcll(b);
    }
    const unsigned long long lt = (lane == 0) ? 0ull : (~0ull >> (64 - lane));
    const int lower = __popcll(myball & lt);
    __syncthreads();
    int base = 0;
    for (int d = 0; d < dev; ++d)
      base += scnt[0 * 8 + d] + scnt[1 * 8 + d] + scnt[2 * 8 + d] +
              scnt[3 * 8 + d];
    for (int w2 = 0; w2 < w; ++w2) base += scnt[w2 * 8 + dev];
    spos[tid] = base + lower;
    __syncthreads();
  }

  // 4) gather the selected score (e arrived long ago; setup hid the latency)
  const float sc = topk[(size_t)tok * E_EXP + e];
  const int pos = spos[e];   // remapped position 0..255
  const int dv  = sdev[e];   // device for the dispatch mask

  // 5) device-mask ballots: bit L of b_d <=> entry L (token L>>3) uses dev d.
  unsigned long long bsel = 0ull;
#pragma unroll
  for (int d = 0; d < D_DEV; ++d) {
    unsigned long long b = __ballot(dv == d);
    if ((lane & 7) == d) bsel = b;
  }
  // lanes 0..31: row r = lane>>3 (token pair 2r,2r+1 -> bits [16r,16r+16))
  const float fm =
      ((bsel >> (16 * (lane >> 3))) & 0xFFFFull) ? 1.0f : 0.0f;
  if (lane < 32)
    out_mask[(size_t)(tbase >> 1) * D_DEV + lane] = fm;  // 128 B contiguous

  // 6) scatter into the dense tile (wave-private; DS pipe is in-order per
  //    wave, so the zero-fill above is already ordered before this write)
  tile[w][(lane >> 3) * E_EXP + pos] = sc;

  // 7) coalesced write-out: lane owns positions [4*lane, 4*lane+4)
  const int dchunk = lane >> 3;          // (4*lane)>>5
  const int j      = (lane * 4) & 31;
  float* const obase =
      out_remap + (size_t)dchunk * T_TOK * SLOTS + j;
#pragma unroll
  for (int tt = 0; tt < TOK_PER_WAVE; ++tt) {
    const float4 v = *(const float4*)&tile[w][tt * E_EXP + lane * 4];
    *(float4*)(obase + (size_t)(tbase + tt) * SLOTS) = v;
  }
}

extern "C" void kernel_launch(void* const* d_in, const int* in_sizes, int n_in,
                              void* d_out, int out_size, void* d_ws, size_t ws_size,
                              hipStream_t stream) {
  const float* topk    = (const float*)d_in[0];
  const int*   mapping = (const int*)d_in[1];
  const int*   meta    = (const int*)d_in[2];

  float* out_remap = (float*)d_out;
  float* out_mask  = out_remap + (size_t)D_DEV * T_TOK * SLOTS;  // 8,388,608

  moe_fused_kernel<<<NBLK, 256, 0, stream>>>(topk, mapping, meta, out_remap,
                                             out_mask);
}